// Round 4
// baseline (235.956 us; speedup 1.0000x reference)
//
#include <hip/hip_runtime.h>
#include <hip/hip_cooperative_groups.h>
#include <hip/hip_bf16.h>
#include <stdint.h>

#define DI __device__ __forceinline__
namespace cg = cooperative_groups;

typedef __attribute__((ext_vector_type(8))) short short8;
typedef __attribute__((ext_vector_type(4))) float f32x4;

constexpr int CH   = 128;
constexpr int FH   = 120;
constexpr int FW   = 120;
constexpr int NBOX = 512;
constexpr int KDIM = 49 * 128;   // 6272
constexpr int D1   = 512;
constexpr int D2   = 256;
constexpr int SPLITS = 14;
constexpr int GEMM_WGS = 16 * SPLITS; // 224

DI float bf2f(uint32_t u16) { union { uint32_t i; float f; } v; v.i = u16 << 16; return v.f; }
DI uint16_t f2bf(float f) {
    __hip_bfloat16 h = __float2bfloat16(f);
    union { __hip_bfloat16 h; uint16_t u; } v; v.h = h; return v.u;
}

// ---------- K1: tfeat (480 blocks) + W2 transpose (32 blocks) ----------
// ft [120,120,128] bf16 packed as u32 pairs; W2T [256][512] bf16.
__global__ __launch_bounds__(256) void k_pre(const float* __restrict__ f,
                                             const float* __restrict__ W2,
                                             uint32_t* __restrict__ ft,
                                             uint16_t* __restrict__ W2T) {
    __shared__ __align__(16) char smem[16896];
    const int v = blockIdx.x, t = threadIdx.x;
    if (v < 480) {
        float* lds = (float*)smem;              // [x:30][c:129 pad]
        const int y = v >> 2, x0 = (v & 3) * 30;
        for (int e = t; e < 30 * 128; e += 256) {
            int c = e / 30, x = e - c * 30;
            lds[x * 129 + c] = f[c * (FH * FW) + y * FW + x0 + x];
        }
        __syncthreads();
        for (int e = t; e < 30 * 64; e += 256) {
            int x = e >> 6, cp = e & 63;
            float lo = lds[x * 129 + 2 * cp];
            float hi = lds[x * 129 + 2 * cp + 1];
            ft[(y * FW + x0 + x) * 64 + cp] = (uint32_t)f2bf(lo) | ((uint32_t)f2bf(hi) << 16);
        }
    } else {
        float* lds = (float*)smem;              // [k:128][n:33 pad]
        const int v2 = v - 480;                 // 0..31
        const int n0 = (v2 & 7) * 32, k0 = (v2 >> 3) * 128;
        for (int e = t; e < 4096; e += 256) {
            int k = e >> 5, nn = e & 31;
            lds[k * 33 + nn] = W2[(k0 + k) * D2 + n0 + nn];
        }
        __syncthreads();
        for (int e = t; e < 4096; e += 256) {
            int nn = e >> 7, k = e & 127;
            W2T[(n0 + nn) * D1 + k0 + k] = f2bf(lds[k * 33 + nn]);
        }
    }
}

// ---------- K2: ROI align (6272 blocks) + W1 transpose (784 blocks) ----------
// A [box][bin][ch] bf16 pairs; W1rT [512][6272] bf16 with k = bin*128 + c.
__global__ __launch_bounds__(256) void k_roi_w1(const uint32_t* __restrict__ ft,
                                                const float* __restrict__ boxes,
                                                const float* __restrict__ W1,
                                                uint32_t* __restrict__ A,
                                                uint16_t* __restrict__ W1rT) {
    __shared__ __align__(16) float lds[128 * 33];
    const int blk = blockIdx.x, t = threadIdx.x;
    if (blk < 6272) {
#pragma clang fp contract(off)
        const int wid  = (blk << 2) + (t >> 6); // 0..25087
        const int lane = t & 63;
        const int box = wid / 49, bin = wid % 49;
        const int ph = bin / 7, pw = bin % 7;

        const float bx = boxes[box * 4 + 0], by = boxes[box * 4 + 1];
        const float bw = boxes[box * 4 + 2], bh = boxes[box * 4 + 3];
        const float x1 = bx * 120.0f - 0.5f;
        const float y1 = by * 120.0f - 0.5f;
        const float roi_w = bw * 120.0f, roi_h = bh * 120.0f;
        const float bin_w = roi_w / 7.0f, bin_h = roi_h / 7.0f;
        const float gwf = fmaxf(ceilf(roi_w / 7.0f), 1.0f);
        const float ghf = fmaxf(ceilf(roi_h / 7.0f), 1.0f);
        const int gwi = (int)gwf, ghi = (int)ghf;

        const float ybase = y1 + (float)ph * bin_h;
        const float xbase = x1 + (float)pw * bin_w;

        float acc0 = 0.0f, acc1 = 0.0f;
        for (int sy = 0; sy < ghi; ++sy) {
            float yy = ybase + ((float)sy + 0.5f) * bin_h / ghf;
            bool vy = (yy > -1.0f) && (yy < 120.0f);
            float yc = fminf(fmaxf(yy, 0.0f), 119.0f);
            int y0 = (int)floorf(yc);
            int yh = min(y0 + 1, 119);
            float ly = yc - (float)y0, hy = 1.0f - ly;
            const uint32_t* r0 = ft + (size_t)(y0 * FW) * 64;
            const uint32_t* r1 = ft + (size_t)(yh * FW) * 64;
            for (int sx = 0; sx < gwi; ++sx) {
                float xx = xbase + ((float)sx + 0.5f) * bin_w / gwf;
                if (!(vy && (xx > -1.0f) && (xx < 120.0f))) continue;
                float xc = fminf(fmaxf(xx, 0.0f), 119.0f);
                int x0 = (int)floorf(xc);
                int xh = min(x0 + 1, 119);
                float lx = xc - (float)x0, hx = 1.0f - lx;
                float w00 = hy * hx, w01 = hy * lx, w10 = ly * hx, w11 = ly * lx;
                uint32_t u00 = r0[x0 * 64 + lane];
                uint32_t u01 = r0[xh * 64 + lane];
                uint32_t u10 = r1[x0 * 64 + lane];
                uint32_t u11 = r1[xh * 64 + lane];
                acc0 += w00 * bf2f(u00 & 0xffffu) + w01 * bf2f(u01 & 0xffffu)
                      + w10 * bf2f(u10 & 0xffffu) + w11 * bf2f(u11 & 0xffffu);
                acc1 += w00 * bf2f(u00 >> 16) + w01 * bf2f(u01 >> 16)
                      + w10 * bf2f(u10 >> 16) + w11 * bf2f(u11 >> 16);
            }
        }
        const float cnt = ghf * gwf;
        const float v0 = acc0 / cnt, v1 = acc1 / cnt;
        A[(size_t)wid * 64 + lane] = (uint32_t)f2bf(v0) | ((uint32_t)f2bf(v1) << 16);
    } else {
        const int vb = blk - 6272;              // 0..783
        const int b = vb % 49, j0 = (vb / 49) * 32;
        for (int e = t; e < 4096; e += 256) {
            int ci = e >> 5, jj = e & 31;
            lds[ci * 33 + jj] = W1[(ci * 49 + b) * D1 + j0 + jj];
        }
        __syncthreads();
        for (int e = t; e < 4096; e += 256) {
            int jj = e >> 7, ci = e & 127;
            W1rT[(size_t)(j0 + jj) * KDIM + b * 128 + ci] = f2bf(lds[ci * 33 + jj]);
        }
    }
}

// ---------- K3: cooperative — gemm1 (split-K) -> reduce+bias+ReLU -> gemm2 ----------
// grid = 224 WGs x 512 thr. gemm1: 128x128 tile, 8 waves (2x4), 4x2 frags/wave,
// BK=32, XOR-swizzled LDS chunks (2-way aliasing = free).
__global__ __launch_bounds__(512) void k_mlp(const uint16_t* __restrict__ A,
                                             const uint16_t* __restrict__ B,
                                             float* __restrict__ P,
                                             const float* __restrict__ b1,
                                             uint16_t* __restrict__ Hm,
                                             const uint16_t* __restrict__ W2T,
                                             const float* __restrict__ b2,
                                             float* __restrict__ out) {
    cg::grid_group grid = cg::this_grid();
    __shared__ __align__(16) uint16_t As[128 * 32];
    __shared__ __align__(16) uint16_t Bs[128 * 32];
    const int wg = blockIdx.x, t = threadIdx.x;
    const int lane = t & 63, w8 = t >> 6;

    // ---- phase 1: GEMM1 split-K ----
    {
        const int s = wg % SPLITS, tl = wg / SPLITS;   // s: 0..13, tl: 0..15
        const int m0 = (tl & 3) * 128, n0 = (tl >> 2) * 128;
        const int kbase = s * 448;
        const int wr = w8 >> 2, wc = w8 & 3;           // 2 x 4 waves
        const int kb = lane >> 4, r16 = lane & 15;
        const int row = t >> 2, c8 = t & 3;            // 512 thr = 128 rows x 4 chunks
        const int ldst = row * 32 + ((c8 ^ ((row >> 1) & 3)) * 8);
        const uint16_t* ga = A + (size_t)(m0 + row) * KDIM + c8 * 8;
        const uint16_t* gb = B + (size_t)(n0 + row) * KDIM + c8 * 8;

        f32x4 acc[4][2] = {};
        for (int ks = 0; ks < 14; ++ks) {
            const int kk = kbase + ks * 32;
            __syncthreads();
            *(uint4*)&As[ldst] = *(const uint4*)&ga[kk];
            *(uint4*)&Bs[ldst] = *(const uint4*)&gb[kk];
            __syncthreads();

            short8 af[4], bfr[2];
#pragma unroll
            for (int mi = 0; mi < 4; ++mi) {
                int ar = wr * 64 + mi * 16 + r16;
                af[mi] = *(const short8*)&As[ar * 32 + (kb ^ ((ar >> 1) & 3)) * 8];
            }
#pragma unroll
            for (int ni = 0; ni < 2; ++ni) {
                int br = wc * 32 + ni * 16 + r16;
                bfr[ni] = *(const short8*)&Bs[br * 32 + (kb ^ ((br >> 1) & 3)) * 8];
            }
#pragma unroll
            for (int mi = 0; mi < 4; ++mi)
#pragma unroll
                for (int ni = 0; ni < 2; ++ni)
                    acc[mi][ni] = __builtin_amdgcn_mfma_f32_16x16x32_bf16(af[mi], bfr[ni], acc[mi][ni], 0, 0, 0);
        }
        float* op = P + (size_t)s * (D1 * D1);
#pragma unroll
        for (int mi = 0; mi < 4; ++mi)
#pragma unroll
            for (int ni = 0; ni < 2; ++ni) {
                int rrow = m0 + wr * 64 + mi * 16 + kb * 4;
                int ccol = n0 + wc * 32 + ni * 16 + r16;
#pragma unroll
                for (int r = 0; r < 4; ++r)
                    op[(size_t)(rrow + r) * D1 + ccol] = acc[mi][ni][r];
            }
    }
    __threadfence();
    grid.sync();

    // ---- phase 2: reduce split-K + bias + ReLU -> Hm bf16 ----
    for (int e = wg * 512 + t; e < D1 * D1; e += GEMM_WGS * 512) {
        float s = 0.0f;
#pragma unroll
        for (int i = 0; i < SPLITS; ++i) s += P[(size_t)i * (D1 * D1) + e];
        s += b1[e & (D1 - 1)];
        Hm[e] = f2bf(fmaxf(s, 0.0f));
    }
    __threadfence();
    grid.sync();

    // ---- phase 3: GEMM2 (one wave per 16x16 tile, streamed from L2) ----
    {
        const int gw = wg * 8 + w8;                    // 0..1791
        if (gw < 512) {
            const int m0 = (gw >> 4) * 16, n0 = (gw & 15) * 16;
            const int g = lane >> 4, i = lane & 15;
            f32x4 acc = {};
#pragma unroll
            for (int kk = 0; kk < D1 / 32; ++kk) {
                short8 a = *(const short8*)&Hm[(m0 + i) * D1 + kk * 32 + g * 8];
                short8 b = *(const short8*)&W2T[(n0 + i) * D1 + kk * 32 + g * 8];
                acc = __builtin_amdgcn_mfma_f32_16x16x32_bf16(a, b, acc, 0, 0, 0);
            }
            const float bias = b2[n0 + i];
#pragma unroll
            for (int r = 0; r < 4; ++r)
                out[(size_t)(m0 + g * 4 + r) * D2 + n0 + i] = acc[r] + bias;
        }
    }
}

extern "C" void kernel_launch(void* const* d_in, const int* in_sizes, int n_in,
                              void* d_out, int out_size, void* d_ws, size_t ws_size,
                              hipStream_t stream) {
    const float* f     = (const float*)d_in[0];
    const float* boxes = (const float*)d_in[1];
    const float* W1    = (const float*)d_in[2];
    const float* b1    = (const float*)d_in[3];
    const float* W2    = (const float*)d_in[4];
    const float* b2    = (const float*)d_in[5];
    float* out = (float*)d_out;

    char* p = (char*)d_ws;
    uint32_t* ft   = (uint32_t*)p; p += (size_t)FH * FW * (CH / 2) * 4;  // 3.7 MB
    uint16_t* W1rT = (uint16_t*)p; p += (size_t)D1 * KDIM * 2;           // 6.4 MB
    uint16_t* W2T  = (uint16_t*)p; p += (size_t)D2 * D1 * 2;             // 0.26 MB
    uint16_t* Ar   = (uint16_t*)p; p += (size_t)NBOX * KDIM * 2;         // 6.4 MB
    float*    Pp   = (float*)p;    p += (size_t)SPLITS * D1 * D1 * 4;    // 14.7 MB
    uint16_t* Hm   = (uint16_t*)p; p += (size_t)D1 * D1 * 2;             // 0.52 MB

    k_pre<<<512, 256, 0, stream>>>(f, W2, ft, W2T);
    k_roi_w1<<<6272 + 784, 256, 0, stream>>>(ft, boxes, W1, (uint32_t*)Ar, W1rT);

    const uint16_t* Ac = Ar; const uint16_t* Bc = W1rT; const uint16_t* W2c = W2T;
    void* args[] = { (void*)&Ac, (void*)&Bc, (void*)&Pp, (void*)&b1,
                     (void*)&Hm, (void*)&W2c, (void*)&b2, (void*)&out };
    hipLaunchCooperativeKernel((const void*)k_mlp, dim3(GEMM_WGS), dim3(512),
                               args, 0, stream);
}

// Round 7
// 72.956 us; speedup vs baseline: 3.2342x; 3.2342x over previous
//
#include <hip/hip_runtime.h>
#include <hip/hip_bf16.h>
#include <stdint.h>

#define DI __device__ __forceinline__

typedef __attribute__((ext_vector_type(8))) short short8;
typedef __attribute__((ext_vector_type(4))) float f32x4;

constexpr int CH   = 128;
constexpr int FH   = 120;
constexpr int FW   = 120;
constexpr int NBOX = 512;
constexpr int KDIM = 49 * 128;   // 6272
constexpr int D1   = 512;
constexpr int D2   = 256;
constexpr int SPLITS = 14;
constexpr int KC     = KDIM / SPLITS; // 448

DI float bf2f(uint32_t u16) { union { uint32_t i; float f; } v; v.i = u16 << 16; return v.f; }
DI uint16_t f2bf(float f) {
    __hip_bfloat16 h = __float2bfloat16(f);
    union { __hip_bfloat16 h; uint16_t u; } v; v.h = h; return v.u;
}

// ---------- K1: all preprocessing in one dispatch ----------
// blocks [0,480): features [128,120,120] f32 -> ft [120,120,128] bf16 (u32 pairs)
// blocks [480,512): W2 [512,256] -> W2T [256][512] bf16
// blocks [512,1296): W1 [6272,512] -> W1rT [512][6272] bf16, k' = b*128 + c
__global__ __launch_bounds__(256) void k_pre(const float* __restrict__ f,
                                             const float* __restrict__ W1,
                                             const float* __restrict__ W2,
                                             uint32_t* __restrict__ ft,
                                             uint16_t* __restrict__ W1rT,
                                             uint16_t* __restrict__ W2T) {
    __shared__ __align__(16) char smem[16896];
    const int v = blockIdx.x, t = threadIdx.x;
    if (v < 480) {
        float* lds = (float*)smem;              // [x:30][c:129 pad]
        const int y = v >> 2, x0 = (v & 3) * 30;
        for (int e = t; e < 30 * 128; e += 256) {
            int c = e / 30, x = e - c * 30;
            lds[x * 129 + c] = f[c * (FH * FW) + y * FW + x0 + x];
        }
        __syncthreads();
        for (int e = t; e < 30 * 64; e += 256) {
            int x = e >> 6, cp = e & 63;
            float lo = lds[x * 129 + 2 * cp];
            float hi = lds[x * 129 + 2 * cp + 1];
            ft[(y * FW + x0 + x) * 64 + cp] = (uint32_t)f2bf(lo) | ((uint32_t)f2bf(hi) << 16);
        }
    } else if (v < 512) {
        float* lds = (float*)smem;              // [k:128][n:33 pad]
        const int v2 = v - 480;                 // 0..31
        const int n0 = (v2 & 7) * 32, k0 = (v2 >> 3) * 128;
        for (int e = t; e < 4096; e += 256) {
            int k = e >> 5, nn = e & 31;
            lds[k * 33 + nn] = W2[(k0 + k) * D2 + n0 + nn];
        }
        __syncthreads();
        for (int e = t; e < 4096; e += 256) {
            int nn = e >> 7, k = e & 127;
            W2T[(n0 + nn) * D1 + k0 + k] = f2bf(lds[k * 33 + nn]);
        }
    } else {
        float* lds = (float*)smem;              // [c:128][j:33 pad]
        const int vb = v - 512;                 // 0..783
        const int b = vb % 49, j0 = (vb / 49) * 32;
        for (int e = t; e < 4096; e += 256) {
            int ci = e >> 5, jj = e & 31;
            lds[ci * 33 + jj] = W1[(ci * 49 + b) * D1 + j0 + jj];
        }
        __syncthreads();
        for (int e = t; e < 4096; e += 256) {
            int jj = e >> 7, ci = e & 127;
            W1rT[(size_t)(j0 + jj) * KDIM + b * 128 + ci] = f2bf(lds[ci * 33 + jj]);
        }
    }
}

// ---------- K2: ROI align: one wave per (box,bin); lane = channel pair ----------
__global__ __launch_bounds__(256) void k_roi(const uint32_t* __restrict__ ft,
                                             const float* __restrict__ boxes,
                                             uint32_t* __restrict__ A) {
#pragma clang fp contract(off)
    const int wid  = (blockIdx.x << 2) + (threadIdx.x >> 6); // 0..25087
    const int lane = threadIdx.x & 63;
    const int box = wid / 49, bin = wid % 49;
    const int ph = bin / 7, pw = bin % 7;

    const float bx = boxes[box * 4 + 0], by = boxes[box * 4 + 1];
    const float bw = boxes[box * 4 + 2], bh = boxes[box * 4 + 3];
    const float x1 = bx * 120.0f - 0.5f;
    const float y1 = by * 120.0f - 0.5f;
    const float roi_w = bw * 120.0f, roi_h = bh * 120.0f;
    const float bin_w = roi_w / 7.0f, bin_h = roi_h / 7.0f;
    const float gwf = fmaxf(ceilf(roi_w / 7.0f), 1.0f);
    const float ghf = fmaxf(ceilf(roi_h / 7.0f), 1.0f);
    const int gwi = (int)gwf, ghi = (int)ghf;

    const float ybase = y1 + (float)ph * bin_h;
    const float xbase = x1 + (float)pw * bin_w;

    float acc0 = 0.0f, acc1 = 0.0f;
    for (int sy = 0; sy < ghi; ++sy) {
        float yy = ybase + ((float)sy + 0.5f) * bin_h / ghf;
        bool vy = (yy > -1.0f) && (yy < 120.0f);
        float yc = fminf(fmaxf(yy, 0.0f), 119.0f);
        int y0 = (int)floorf(yc);
        int yh = min(y0 + 1, 119);
        float ly = yc - (float)y0, hy = 1.0f - ly;
        const uint32_t* r0 = ft + (size_t)(y0 * FW) * 64;
        const uint32_t* r1 = ft + (size_t)(yh * FW) * 64;
        for (int sx = 0; sx < gwi; ++sx) {
            float xx = xbase + ((float)sx + 0.5f) * bin_w / gwf;
            if (!(vy && (xx > -1.0f) && (xx < 120.0f))) continue;
            float xc = fminf(fmaxf(xx, 0.0f), 119.0f);
            int x0 = (int)floorf(xc);
            int xh = min(x0 + 1, 119);
            float lx = xc - (float)x0, hx = 1.0f - lx;
            float w00 = hy * hx, w01 = hy * lx, w10 = ly * hx, w11 = ly * lx;
            uint32_t u00 = r0[x0 * 64 + lane];
            uint32_t u01 = r0[xh * 64 + lane];
            uint32_t u10 = r1[x0 * 64 + lane];
            uint32_t u11 = r1[xh * 64 + lane];
            acc0 += w00 * bf2f(u00 & 0xffffu) + w01 * bf2f(u01 & 0xffffu)
                  + w10 * bf2f(u10 & 0xffffu) + w11 * bf2f(u11 & 0xffffu);
            acc1 += w00 * bf2f(u00 >> 16) + w01 * bf2f(u01 >> 16)
                  + w10 * bf2f(u10 >> 16) + w11 * bf2f(u11 >> 16);
        }
    }
    const float cnt = ghf * gwf;
    const float v0 = acc0 / cnt, v1 = acc1 / cnt;
    A[(size_t)wid * 64 + lane] = (uint32_t)f2bf(v0) | ((uint32_t)f2bf(v1) << 16);
}

// ---------- K3: GEMM1 split-K (proven round-3 version) ----------
__global__ __launch_bounds__(256) void k_gemm1(const uint16_t* __restrict__ A,
                                               const uint16_t* __restrict__ B,
                                               float* __restrict__ P) {
    __shared__ __align__(16) uint16_t As[128 * 32];
    __shared__ __align__(16) uint16_t Bs[128 * 32];
    const int t = threadIdx.x;
    const int lane = t & 63, w = t >> 6;
    const int wr = w >> 1, wc = w & 1;
    const int m0 = blockIdx.x * 128, n0 = blockIdx.y * 128;
    const int kbase = blockIdx.z * KC;

    f32x4 acc[4][4] = {};
    const int kb = lane >> 4, r16 = lane & 15;

    for (int ks = 0; ks < KC / 32; ++ks) {
        const int kk = kbase + ks * 32;
        __syncthreads();
#pragma unroll
        for (int i = 0; i < 2; ++i) {
            int ch = t + 256 * i;
            int row = ch >> 2, c8 = ch & 3;
            int sw = (row >> 1) & 3;
            const uint16_t* ga = A + (size_t)(m0 + row) * KDIM + kk + c8 * 8;
            *(uint4*)&As[row * 32 + (c8 ^ sw) * 8] = *(const uint4*)ga;
            const uint16_t* gb = B + (size_t)(n0 + row) * KDIM + kk + c8 * 8;
            *(uint4*)&Bs[row * 32 + (c8 ^ sw) * 8] = *(const uint4*)gb;
        }
        __syncthreads();

        short8 af[4], bfr[4];
#pragma unroll
        for (int mi = 0; mi < 4; ++mi) {
            int ar = wr * 64 + mi * 16 + r16;
            af[mi] = *(const short8*)&As[ar * 32 + (kb ^ ((ar >> 1) & 3)) * 8];
        }
#pragma unroll
        for (int ni = 0; ni < 4; ++ni) {
            int br = wc * 64 + ni * 16 + r16;
            bfr[ni] = *(const short8*)&Bs[br * 32 + (kb ^ ((br >> 1) & 3)) * 8];
        }
#pragma unroll
        for (int mi = 0; mi < 4; ++mi)
#pragma unroll
            for (int ni = 0; ni < 4; ++ni)
                acc[mi][ni] = __builtin_amdgcn_mfma_f32_16x16x32_bf16(af[mi], bfr[ni], acc[mi][ni], 0, 0, 0);
    }

    float* outp = P + (size_t)blockIdx.z * (D1 * D1);
#pragma unroll
    for (int mi = 0; mi < 4; ++mi)
#pragma unroll
        for (int ni = 0; ni < 4; ++ni) {
            int row = m0 + wr * 64 + mi * 16 + kb * 4;
            int col = n0 + wc * 64 + ni * 16 + r16;
#pragma unroll
            for (int r = 0; r < 4; ++r)
                outp[(size_t)(row + r) * D1 + col] = acc[mi][ni][r];
        }
}

// ---------- K4: reduce split-K + bias + ReLU -> H bf16, vectorized x4 ----------
__global__ __launch_bounds__(256) void k_reduce1(const float* __restrict__ P,
                                                 const float* __restrict__ b1,
                                                 uint16_t* __restrict__ Hm) {
    const int e4 = blockIdx.x * 256 + threadIdx.x;  // 65536 f32x4 groups
    const f32x4* P4 = (const f32x4*)P;
    f32x4 s = {};
#pragma unroll
    for (int i = 0; i < SPLITS; ++i) s += P4[(size_t)i * (D1 * D1 / 4) + e4];
    const int c4 = (e4 & 127) * 4;
    uint16_t h[4];
#pragma unroll
    for (int j = 0; j < 4; ++j) h[j] = f2bf(fmaxf(s[j] + b1[c4 + j], 0.0f));
    uint2 pk;
    pk.x = (uint32_t)h[0] | ((uint32_t)h[1] << 16);
    pk.y = (uint32_t)h[2] | ((uint32_t)h[3] << 16);
    *(uint2*)&Hm[(size_t)e4 * 4] = pk;
}

// ---------- K5: GEMM2 (proven round-3 version) ----------
__global__ __launch_bounds__(256) void k_gemm2(const uint16_t* __restrict__ Hm,
                                               const uint16_t* __restrict__ W2T,
                                               const float* __restrict__ b2,
                                               float* __restrict__ out) {
    const int wid  = blockIdx.x * 4 + (threadIdx.x >> 6); // 0..511
    const int lane = threadIdx.x & 63;
    const int mt = wid >> 4, nt = wid & 15;
    const int m0 = mt * 16, n0 = nt * 16;
    const int g = lane >> 4, i = lane & 15;
    f32x4 acc = {};
#pragma unroll
    for (int kk = 0; kk < D1 / 32; ++kk) {
        short8 a = *(const short8*)&Hm[(m0 + i) * D1 + kk * 32 + g * 8];
        short8 b = *(const short8*)&W2T[(n0 + i) * D1 + kk * 32 + g * 8];
        acc = __builtin_amdgcn_mfma_f32_16x16x32_bf16(a, b, acc, 0, 0, 0);
    }
    const float bias = b2[n0 + i];
#pragma unroll
    for (int r = 0; r < 4; ++r)
        out[(size_t)(m0 + g * 4 + r) * D2 + n0 + i] = acc[r] + bias;
}

extern "C" void kernel_launch(void* const* d_in, const int* in_sizes, int n_in,
                              void* d_out, int out_size, void* d_ws, size_t ws_size,
                              hipStream_t stream) {
    const float* f     = (const float*)d_in[0];
    const float* boxes = (const float*)d_in[1];
    const float* W1    = (const float*)d_in[2];
    const float* b1    = (const float*)d_in[3];
    const float* W2    = (const float*)d_in[4];
    const float* b2    = (const float*)d_in[5];
    float* out = (float*)d_out;

    char* p = (char*)d_ws;
    uint32_t* ft   = (uint32_t*)p; p += (size_t)FH * FW * (CH / 2) * 4;  // 3.7 MB
    uint16_t* W1rT = (uint16_t*)p; p += (size_t)D1 * KDIM * 2;           // 6.4 MB
    uint16_t* W2T  = (uint16_t*)p; p += (size_t)D2 * D1 * 2;             // 0.26 MB
    uint16_t* Ar   = (uint16_t*)p; p += (size_t)NBOX * KDIM * 2;         // 6.4 MB
    float*    Pp   = (float*)p;    p += (size_t)SPLITS * D1 * D1 * 4;    // 14.7 MB
    uint16_t* Hm   = (uint16_t*)p; p += (size_t)D1 * D1 * 2;             // 0.52 MB

    k_pre<<<1296, 256, 0, stream>>>(f, W1, W2, ft, W1rT, W2T);
    k_roi<<<(NBOX * 49) / 4, 256, 0, stream>>>(ft, boxes, (uint32_t*)Ar);
    k_gemm1<<<dim3(4, 4, SPLITS), 256, 0, stream>>>(Ar, W1rT, Pp);
    k_reduce1<<<D1 * D1 / 4 / 256, 256, 0, stream>>>(Pp, b1, Hm);
    k_gemm2<<<(D1 / 16) * (D2 / 16) / 4, 256, 0, stream>>>(Hm, W2T, b2, out);
}